// Round 5
// baseline (113.164 us; speedup 1.0000x reference)
//
#include <hip/hip_runtime.h>
#include <math.h>

#define NSEG 20001      // I_DIM + 1 segments / items
#define EMB  128
#define NE   640000

#define SCALE_BLOCKS 313         // ceil(NSEG/64) : 64 rows per block
#define BOUNDS_BLOCKS 2500       // NE/256 exact
#define APAD 136                 // bf16 elems per LDS A-row: 272B stride -> bank step 4, ~2-way max
#define WROWS 144                // wt allocation rows: 128 W cols + wfs/wfd + 14 pad (read-only garbage)

typedef __attribute__((ext_vector_type(8))) short bf16x8;   // 8 bf16 = 4 VGPRs
typedef __attribute__((ext_vector_type(4))) float f32x4;    // MFMA C/D

__device__ __forceinline__ unsigned f2bf(float x) {
    unsigned u = __float_as_uint(x);
    return (u + 0x7fffu + ((u >> 16) & 1u)) >> 16;   // round-nearest-even bf16 bits
}
__device__ __forceinline__ float bfbits2f(unsigned h) { return __uint_as_float(h << 16); }

// One-shot: W (f32 [k][col]) -> wt_hi/wt_lo (bf16 [col][k], B^T frag-ready).
// Blocks 0..15: the 128 W columns. Block 16: fused attention columns
//   wf_s = W @ Watt[0:128], wf_d = W @ Watt[128:256]  (stored as rows 128/129)
// plus scalar biases bfuse[] = bsc @ Watt halves. hi/lo split throughout.
__global__ __launch_bounds__(256) void wconv_kernel(
    const float* __restrict__ W, const float* __restrict__ Watt,
    const float* __restrict__ bsc,
    unsigned short* __restrict__ wt_hi, unsigned short* __restrict__ wt_lo,
    float* __restrict__ bfuse)
{
    if (blockIdx.x == 16) {
        const int k     = threadIdx.x & 127;
        const int which = threadIdx.x >> 7;        // 0 -> src, 1 -> dst
        const float* wa = Watt + which * EMB;
        float acc = 0.f;
        for (int c = 0; c < EMB; ++c) acc += W[k * EMB + c] * wa[c];
        unsigned h = f2bf(acc);
        unsigned l = f2bf(acc - bfbits2f(h));
        wt_hi[(EMB + which) * EMB + k] = (unsigned short)h;
        wt_lo[(EMB + which) * EMB + k] = (unsigned short)l;
        if (k == 0) {
            float b = 0.f;
            for (int c = 0; c < EMB; ++c) b += bsc[c] * wa[c];
            bfuse[which] = b;
        }
        return;
    }
    const int c  = blockIdx.x * 8 + (threadIdx.x & 7);
    const int k0 = (threadIdx.x >> 3) * 4;
    unsigned h[4], l[4];
    #pragma unroll
    for (int i = 0; i < 4; ++i) {
        float x = W[(k0 + i) * EMB + c];
        h[i] = f2bf(x);
        l[i] = f2bf(x - bfbits2f(h[i]));
    }
    *(uint2*)&wt_hi[c * EMB + k0] = make_uint2(h[0] | (h[1] << 16), h[2] | (h[3] << 16));
    *(uint2*)&wt_lo[c * EMB + k0] = make_uint2(l[0] | (l[1] << 16), l[2] | (l[3] << 16));
}

// Fused prep:
//  blocks [0, SCALE_BLOCKS): item_scaled via 3-pass split-bf16 MFMA (16x16x32).
//    64 rows/block, 4 waves; wave w owns n-tiles {w, w+4}. Wave 0 additionally
//    computes a 9th n-tile against B-rows 128/129 (the wconv-fused attention
//    vectors) -> a_src/a_dst come straight out of the MFMA accumulator: the
//    old epilogue's 128 __shfl_xor DS-ops, LDS partial buffers, second
//    __syncthreads and tail block are all gone. Rows 130..143 of wt are
//    poisoned-but-allocated; they only feed unused acc columns (MFMA output
//    columns are independent), so the garbage never escapes.
//  blocks [SCALE_BLOCKS, +BOUNDS_BLOCKS): segment bounds + dst compaction.
__global__ __launch_bounds__(256) void prep_kernel(
    const float* __restrict__ emb,
    const unsigned short* __restrict__ wt_hi, const unsigned short* __restrict__ wt_lo,
    const float* __restrict__ bsc, const float* __restrict__ bfuse,
    const int* __restrict__ edge,
    unsigned short* __restrict__ tab,       // bf16 tab: dword j of row = feats (j, j+64)
    float* __restrict__ a_src, float* __restrict__ a_dst,
    int* __restrict__ seg_start, int* __restrict__ dst)
{
    const int tid = threadIdx.x;
    if (blockIdx.x >= SCALE_BLOCKS) {
        // ---- bounds + dst-compaction ----
        int e = (blockIdx.x - SCALE_BLOCKS) * 256 + tid;
        int2 p = ((const int2*)edge)[e];            // coalesced 8B
        dst[e] = p.y;
        int sp = __shfl_up(p.x, 1);
        if ((tid & 63) == 0) sp = (e == 0) ? -1 : edge[2*e - 2];
        for (int t = sp + 1; t <= p.x; ++t) seg_start[t] = e;
        if (e == NE - 1) {
            for (int t = p.x + 1; t <= NSEG; ++t) seg_start[t] = NE;
        }
        return;
    }

    // ---- scale branch: MFMA ----
    __shared__ unsigned short Ah[64 * APAD];   // 17.0 KB
    __shared__ unsigned short Al[64 * APAD];   // 17.0 KB -> 34 KB, 4 blocks/CU

    const int r0   = blockIdx.x * 64;
    const int w    = tid >> 6;          // wave id: n-tiles {w, w+4}
    const int lane = tid & 63;
    const int l15  = lane & 15;
    const int lk   = lane >> 4;

    // emb tile -> bf16 hi/lo in LDS (padded row-major [64][APAD])
    const float4* embg4 = (const float4*)emb;
    const int gmax = NSEG * 32 - 1;
    #pragma unroll
    for (int j = 0; j < 8; ++j) {
        int idx = tid + j * 256;            // 0..2047 float4 slots
        int row = idx >> 5, f4 = idx & 31;
        int g = r0 * 32 + idx;
        float4 v = embg4[g <= gmax ? g : gmax];
        unsigned h0 = f2bf(v.x), h1 = f2bf(v.y), h2 = f2bf(v.z), h3 = f2bf(v.w);
        unsigned l0 = f2bf(v.x - bfbits2f(h0)), l1 = f2bf(v.y - bfbits2f(h1));
        unsigned l2 = f2bf(v.z - bfbits2f(h2)), l3 = f2bf(v.w - bfbits2f(h3));
        int o = row * APAD + f4 * 4;
        *(uint2*)&Ah[o] = make_uint2(h0 | (h1 << 16), h2 | (h3 << 16));
        *(uint2*)&Al[o] = make_uint2(l0 | (l1 << 16), l2 | (l3 << 16));
    }
    __syncthreads();

    const int c0 = w * 16 + l15;        // n-tile w
    const int c1 = c0 + 64;             // n-tile w+4
    const bf16x8* Bh0p = (const bf16x8*)&wt_hi[c0 * EMB];
    const bf16x8* Bh1p = (const bf16x8*)&wt_hi[c1 * EMB];
    const bf16x8* Bl0p = (const bf16x8*)&wt_lo[c0 * EMB];
    const bf16x8* Bl1p = (const bf16x8*)&wt_lo[c1 * EMB];
    const bf16x8* Bh8p = (const bf16x8*)&wt_hi[(EMB + l15) * EMB];  // fused att cols
    const bf16x8* Bl8p = (const bf16x8*)&wt_lo[(EMB + l15) * EMB];

    f32x4 acc[4][2];
    f32x4 acc8[4];
    #pragma unroll
    for (int m = 0; m < 4; ++m) {
        acc[m][0] = (f32x4){0.f, 0.f, 0.f, 0.f};
        acc[m][1] = (f32x4){0.f, 0.f, 0.f, 0.f};
        acc8[m]   = (f32x4){0.f, 0.f, 0.f, 0.f};
    }

    #pragma unroll
    for (int kt = 0; kt < 4; ++kt) {
        const int fo = kt * 4 + lk;                 // bf16x8 index into [col][128]
        bf16x8 Bh0 = Bh0p[fo], Bh1 = Bh1p[fo];
        bf16x8 Bl0 = Bl0p[fo], Bl1 = Bl1p[fo];
        bf16x8 Bh8 = {}, Bl8 = {};
        if (w == 0) { Bh8 = Bh8p[fo]; Bl8 = Bl8p[fo]; }
        #pragma unroll
        for (int m = 0; m < 4; ++m) {
            const int ao = (m * 16 + l15) * APAD + kt * 32 + lk * 8;
            bf16x8 Af = *(const bf16x8*)&Ah[ao];
            bf16x8 Lf = *(const bf16x8*)&Al[ao];
            acc[m][0] = __builtin_amdgcn_mfma_f32_16x16x32_bf16(Af, Bh0, acc[m][0], 0, 0, 0);
            acc[m][1] = __builtin_amdgcn_mfma_f32_16x16x32_bf16(Af, Bh1, acc[m][1], 0, 0, 0);
            acc[m][0] = __builtin_amdgcn_mfma_f32_16x16x32_bf16(Lf, Bh0, acc[m][0], 0, 0, 0);
            acc[m][1] = __builtin_amdgcn_mfma_f32_16x16x32_bf16(Lf, Bh1, acc[m][1], 0, 0, 0);
            acc[m][0] = __builtin_amdgcn_mfma_f32_16x16x32_bf16(Af, Bl0, acc[m][0], 0, 0, 0);
            acc[m][1] = __builtin_amdgcn_mfma_f32_16x16x32_bf16(Af, Bl1, acc[m][1], 0, 0, 0);
            if (w == 0) {
                acc8[m] = __builtin_amdgcn_mfma_f32_16x16x32_bf16(Af, Bh8, acc8[m], 0, 0, 0);
                acc8[m] = __builtin_amdgcn_mfma_f32_16x16x32_bf16(Lf, Bh8, acc8[m], 0, 0, 0);
                acc8[m] = __builtin_amdgcn_mfma_f32_16x16x32_bf16(Af, Bl8, acc8[m], 0, 0, 0);
            }
        }
    }

    // epilogue: bias, tab pack (feat c0 | feat c0+64); wave 0 lanes l15<2 store
    // a_src/a_dst straight from the fused-column accumulator.
    const float bs0 = bsc[c0], bs1 = bsc[c1];
    float bf = 0.f;
    if (w == 0 && l15 < 2) bf = bfuse[l15];

    #pragma unroll
    for (int m = 0; m < 4; ++m) {
        #pragma unroll
        for (int r = 0; r < 4; ++r) {
            float v0 = acc[m][0][r] + bs0;
            float v1 = acc[m][1][r] + bs1;
            const int rl  = m * 16 + lk * 4 + r;     // local row (C/D layout)
            const int row = r0 + rl;
            if (row < NSEG) {
                ((unsigned*)tab)[row * 64 + c0] = f2bf(v0) | (f2bf(v1) << 16);
                if (w == 0 && l15 < 2) {
                    float v8 = acc8[m][r] + bf;      // col l15: 0 -> ps, 1 -> pd
                    if (l15 == 0) a_src[row] = v8; else a_dst[row] = v8;
                }
            }
        }
    }
}

__device__ __forceinline__ float bf_lo(unsigned u) { return __uint_as_float(u << 16); }
__device__ __forceinline__ float bf_hi(unsigned u) { return __uint_as_float(u & 0xffff0000u); }
__device__ __forceinline__ float bcastf(float v, int j) {
    return __uint_as_float(__builtin_amdgcn_readlane(__float_as_uint(v), j));
}

// agg: one wave per segment; lane l owns features {l, l+64} (one bf16x2 dword,
// matching the tab packing). Proven structure — byte-identical to round 4.
__global__ __launch_bounds__(256) void agg_kernel(
    const int* __restrict__ dst, const float* __restrict__ a_src,
    const float* __restrict__ a_dst, const float* __restrict__ b_att,
    const int* __restrict__ seg_start, const unsigned int* __restrict__ tab32,
    float* __restrict__ out)
{
    const int wid = blockIdx.x * 4 + (threadIdx.x >> 6);
    if (wid >= NSEG) return;                 // wave-uniform exit
    const int lane = threadIdx.x & 63;
    const unsigned int* tabl = tab32 + lane; // row stride 64 dwords

    const int s0 = seg_start[wid];
    const int s1 = seg_start[wid + 1];
    const float aS = a_src[wid] + b_att[0];

    float accx = 0.f, accy = 0.f, ssum = 0.f;

    for (int cb = s0; cb < s1; cb += 64) {
        int n = s1 - cb; if (n > 64) n = 64;
        int e = cb + lane;
        int dmine = 0; float sc = 0.f;
        if (lane < n) {
            dmine = dst[e] << 6;             // pre-scaled dword row offset
            float att = aS + a_dst[dmine >> 6];
            att = att > 0.f ? att : 0.2f * att;   // leaky_relu 0.2
            sc  = expf(att - 1.f);
        }
        ssum += sc;

        int j = 0;
        for (; j + 7 < n; j += 8) {
            float w0 = bcastf(sc, j+0), w1 = bcastf(sc, j+1);
            float w2 = bcastf(sc, j+2), w3 = bcastf(sc, j+3);
            float w4 = bcastf(sc, j+4), w5 = bcastf(sc, j+5);
            float w6 = bcastf(sc, j+6), w7 = bcastf(sc, j+7);
            int d0 = __builtin_amdgcn_readlane(dmine, j+0);
            int d1 = __builtin_amdgcn_readlane(dmine, j+1);
            int d2 = __builtin_amdgcn_readlane(dmine, j+2);
            int d3 = __builtin_amdgcn_readlane(dmine, j+3);
            int d4 = __builtin_amdgcn_readlane(dmine, j+4);
            int d5 = __builtin_amdgcn_readlane(dmine, j+5);
            int d6 = __builtin_amdgcn_readlane(dmine, j+6);
            int d7 = __builtin_amdgcn_readlane(dmine, j+7);
            unsigned u0 = tabl[d0], u1 = tabl[d1], u2 = tabl[d2], u3 = tabl[d3];
            unsigned u4 = tabl[d4], u5 = tabl[d5], u6 = tabl[d6], u7 = tabl[d7];
            accx += w0 * bf_lo(u0); accy += w0 * bf_hi(u0);
            accx += w1 * bf_lo(u1); accy += w1 * bf_hi(u1);
            accx += w2 * bf_lo(u2); accy += w2 * bf_hi(u2);
            accx += w3 * bf_lo(u3); accy += w3 * bf_hi(u3);
            accx += w4 * bf_lo(u4); accy += w4 * bf_hi(u4);
            accx += w5 * bf_lo(u5); accy += w5 * bf_hi(u5);
            accx += w6 * bf_lo(u6); accy += w6 * bf_hi(u6);
            accx += w7 * bf_lo(u7); accy += w7 * bf_hi(u7);
        }
        for (; j < n; ++j) {
            float w = bcastf(sc, j);
            int   d = __builtin_amdgcn_readlane(dmine, j);
            unsigned u = tabl[d];
            accx += w * bf_lo(u);
            accy += w * bf_hi(u);
        }
    }

    #pragma unroll
    for (int off = 32; off >= 1; off >>= 1) ssum += __shfl_xor(ssum, off);

    const float inv = (s1 > s0) ? 1.f / ssum : 0.f;
    float ox = accx * inv, oy = accy * inv;
    ox = 1.f / (1.f + expf(-ox));
    oy = 1.f / (1.f + expf(-oy));
    out[wid * EMB + lane]      = ox;   // feat lane
    out[wid * EMB + 64 + lane] = oy;   // feat lane+64
}

extern "C" void kernel_launch(void* const* d_in, const int* in_sizes, int n_in,
                              void* d_out, int out_size, void* d_ws, size_t ws_size,
                              hipStream_t stream) {
    const float* emb  = (const float*)d_in[0];   // (20001, 128)
    const int*   edge = (const int*)  d_in[1];   // (640000, 2)
    const float* W    = (const float*)d_in[2];   // (128, 128)
    const float* bsc  = (const float*)d_in[3];   // (128,)
    const float* Watt = (const float*)d_in[4];   // (256,)
    const float* batt = (const float*)d_in[5];   // (1,)
    float* out = (float*)d_out;                  // (20001, 128)

    unsigned short* tab = (unsigned short*)d_ws;            // NSEG*EMB bf16 (5.12 MB)
    float* a_src = (float*)(tab + (size_t)NSEG * EMB);      // NSEG
    float* a_dst = a_src + NSEG;                            // NSEG
    int*   seg_start = (int*)(a_dst + NSEG);                // NSEG+1
    int*   dstc = seg_start + NSEG + 3;                     // NE (compacted dst col)
    unsigned short* wt_hi = (unsigned short*)((char*)d_ws + (32u << 20));  // WROWS x 128 bf16
    unsigned short* wt_lo = wt_hi + WROWS * EMB;                           // WROWS x 128 bf16
    float* bfuse = (float*)(wt_lo + WROWS * EMB);                          // 2 floats

    wconv_kernel<<<17, 256, 0, stream>>>(W, Watt, bsc, wt_hi, wt_lo, bfuse);
    prep_kernel<<<SCALE_BLOCKS + BOUNDS_BLOCKS, 256, 0, stream>>>(
        emb, wt_hi, wt_lo, bsc, bfuse, edge, tab, a_src, a_dst, seg_start, dstc);
    agg_kernel<<<(NSEG + 3) / 4, 256, 0, stream>>>(
        dstc, a_src, a_dst, batt, seg_start, (const unsigned int*)tab, out);
}

// Round 6
// 102.368 us; speedup vs baseline: 1.1055x; 1.1055x over previous
//
#include <hip/hip_runtime.h>
#include <math.h>

#define NSEG 20001      // I_DIM + 1 segments / items
#define EMB  128
#define NE   640000

#define SCALE_BLOCKS 313         // ceil(NSEG/64) : 64 rows per block
#define BOUNDS_BLOCKS 2500       // NE/256 exact
#define APAD 136                 // bf16 elems per LDS A-row: 272B stride -> bank step 4, ~2-way max

typedef __attribute__((ext_vector_type(8))) short bf16x8;   // 8 bf16 = 4 VGPRs
typedef __attribute__((ext_vector_type(4))) float f32x4;    // MFMA C/D

// HW packed f32->bf16 (RNE), lo half = first operand. T12 recipe (no builtin).
__device__ __forceinline__ unsigned cvt_pk_bf16(float lo, float hi) {
    unsigned r;
    asm("v_cvt_pk_bf16_f32 %0, %1, %2" : "=v"(r) : "v"(lo), "v"(hi));
    return r;
}
__device__ __forceinline__ float bfbits2f_lo(unsigned p) { return __uint_as_float(p << 16); }
__device__ __forceinline__ float bfbits2f_hi(unsigned p) { return __uint_as_float(p & 0xffff0000u); }

__device__ __forceinline__ bf16x8 pack4(unsigned a, unsigned b, unsigned c, unsigned d) {
    union { unsigned u[4]; bf16x8 v; } t;
    t.u[0] = a; t.u[1] = b; t.u[2] = c; t.u[3] = d;
    return t.v;
}

// Fused prep (2-kernel pipeline: wconv eliminated):
//  blocks [0, SCALE_BLOCKS): item_scaled via 3-pass split-bf16 MFMA (16x16x32).
//    64 rows/block, 4 waves; wave w owns n-tiles {w, w+4}. Each wave builds its
//    own B-fragments straight from f32 W (per kt: 16 strided dword loads — 4
//    cachelines/instruction, L2-hot since every block reads the same 64 KB —
//    + v_cvt_pk hi/lo split). This removes the wconv kernel and its launch gap.
//    All f32->bf16 conversion uses v_cvt_pk_bf16_f32 (RNE, ties-to-even
//    identical to the old manual f2bf) — fill VALU drops ~2x.
//    Verified layouts (m89/m91): A-frag A[M][K] bf16x8 @ [(lane&15)][(lane>>4)*8],
//    B-frag B^T[N][K] same pattern, C/D col=lane&15,row=(lane>>4)*4+reg.
//    Epilogue = R4 proven form (shuffle-reduce att dots, LDS cross-wave sum).
//  blocks [SCALE_BLOCKS, +BOUNDS_BLOCKS): segment bounds + dst compaction.
__global__ __launch_bounds__(256) void prep_kernel(
    const float* __restrict__ emb, const float* __restrict__ W,
    const float* __restrict__ bsc, const float* __restrict__ Watt,
    const int* __restrict__ edge,
    unsigned short* __restrict__ tab,       // bf16 tab: dword j of row = feats (j, j+64)
    float* __restrict__ a_src, float* __restrict__ a_dst,
    int* __restrict__ seg_start, int* __restrict__ dst)
{
    const int tid = threadIdx.x;
    if (blockIdx.x >= SCALE_BLOCKS) {
        // ---- bounds + dst-compaction ----
        int e = (blockIdx.x - SCALE_BLOCKS) * 256 + tid;
        int2 p = ((const int2*)edge)[e];            // coalesced 8B
        dst[e] = p.y;
        int sp = __shfl_up(p.x, 1);
        if ((tid & 63) == 0) sp = (e == 0) ? -1 : edge[2*e - 2];
        for (int t = sp + 1; t <= p.x; ++t) seg_start[t] = e;
        if (e == NE - 1) {
            for (int t = p.x + 1; t <= NSEG; ++t) seg_start[t] = NE;
        }
        return;
    }

    // ---- scale branch: MFMA ----
    __shared__ unsigned short Ah[64 * APAD];   // 17.0 KB
    __shared__ unsigned short Al[64 * APAD];   // 17.0 KB
    __shared__ float ps_part[4][64];
    __shared__ float pd_part[4][64];           // ~36 KB total

    const int r0   = blockIdx.x * 64;
    const int w    = tid >> 6;          // wave id: n-tiles {w, w+4}
    const int lane = tid & 63;
    const int l15  = lane & 15;
    const int lk   = lane >> 4;

    // emb tile -> bf16 hi/lo in LDS (padded row-major [64][APAD])
    const float4* embg4 = (const float4*)emb;
    const int gmax = NSEG * 32 - 1;
    #pragma unroll
    for (int j = 0; j < 8; ++j) {
        int idx = tid + j * 256;            // 0..2047 float4 slots
        int row = idx >> 5, f4 = idx & 31;
        int g = r0 * 32 + idx;
        float4 v = embg4[g <= gmax ? g : gmax];
        unsigned h01 = cvt_pk_bf16(v.x, v.y);
        unsigned h23 = cvt_pk_bf16(v.z, v.w);
        unsigned l01 = cvt_pk_bf16(v.x - bfbits2f_lo(h01), v.y - bfbits2f_hi(h01));
        unsigned l23 = cvt_pk_bf16(v.z - bfbits2f_lo(h23), v.w - bfbits2f_hi(h23));
        int o = row * APAD + f4 * 4;
        *(uint2*)&Ah[o] = make_uint2(h01, h23);
        *(uint2*)&Al[o] = make_uint2(l01, l23);
    }
    __syncthreads();

    const int c0 = w * 16 + l15;        // n-tile w
    const int c1 = c0 + 64;             // n-tile w+4
    const float* Wc0 = W + c0;          // column stripes (stride EMB)
    const float* Wc1 = W + c1;

    f32x4 acc[4][2];
    #pragma unroll
    for (int m = 0; m < 4; ++m) {
        acc[m][0] = (f32x4){0.f, 0.f, 0.f, 0.f};
        acc[m][1] = (f32x4){0.f, 0.f, 0.f, 0.f};
    }

    #pragma unroll
    for (int kt = 0; kt < 4; ++kt) {
        const int kb = kt * 32 + lk * 8;           // this lane's k-offset
        // build B-frags for cols c0/c1 from f32 W: 16 strided loads + cvt_pk
        float x0[8], x1[8];
        #pragma unroll
        for (int i = 0; i < 8; ++i) {
            x0[i] = Wc0[(kb + i) * EMB];
            x1[i] = Wc1[(kb + i) * EMB];
        }
        unsigned bh0[4], bl0[4], bh1[4], bl1[4];
        #pragma unroll
        for (int i = 0; i < 4; ++i) {
            unsigned h0 = cvt_pk_bf16(x0[2*i], x0[2*i+1]);
            unsigned h1 = cvt_pk_bf16(x1[2*i], x1[2*i+1]);
            bl0[i] = cvt_pk_bf16(x0[2*i] - bfbits2f_lo(h0), x0[2*i+1] - bfbits2f_hi(h0));
            bl1[i] = cvt_pk_bf16(x1[2*i] - bfbits2f_lo(h1), x1[2*i+1] - bfbits2f_hi(h1));
            bh0[i] = h0; bh1[i] = h1;
        }
        bf16x8 Bh0 = pack4(bh0[0], bh0[1], bh0[2], bh0[3]);
        bf16x8 Bh1 = pack4(bh1[0], bh1[1], bh1[2], bh1[3]);
        bf16x8 Bl0 = pack4(bl0[0], bl0[1], bl0[2], bl0[3]);
        bf16x8 Bl1 = pack4(bl1[0], bl1[1], bl1[2], bl1[3]);

        #pragma unroll
        for (int m = 0; m < 4; ++m) {
            const int ao = (m * 16 + l15) * APAD + kt * 32 + lk * 8;
            bf16x8 Af = *(const bf16x8*)&Ah[ao];
            bf16x8 Lf = *(const bf16x8*)&Al[ao];
            acc[m][0] = __builtin_amdgcn_mfma_f32_16x16x32_bf16(Af, Bh0, acc[m][0], 0, 0, 0);
            acc[m][1] = __builtin_amdgcn_mfma_f32_16x16x32_bf16(Af, Bh1, acc[m][1], 0, 0, 0);
            acc[m][0] = __builtin_amdgcn_mfma_f32_16x16x32_bf16(Lf, Bh0, acc[m][0], 0, 0, 0);
            acc[m][1] = __builtin_amdgcn_mfma_f32_16x16x32_bf16(Lf, Bh1, acc[m][1], 0, 0, 0);
            acc[m][0] = __builtin_amdgcn_mfma_f32_16x16x32_bf16(Af, Bl0, acc[m][0], 0, 0, 0);
            acc[m][1] = __builtin_amdgcn_mfma_f32_16x16x32_bf16(Af, Bl1, acc[m][1], 0, 0, 0);
        }
    }

    // epilogue (R4 proven): bias, tab pack (feat c0 | feat c0+64), att dots
    // via 16-col shuffle reduce + cross-wave LDS sum.
    const float bs0 = bsc[c0],        bs1 = bsc[c1];
    const float ws0 = Watt[c0],       ws1 = Watt[c1];
    const float wd0 = Watt[EMB + c0], wd1 = Watt[EMB + c1];

    #pragma unroll
    for (int m = 0; m < 4; ++m) {
        #pragma unroll
        for (int r = 0; r < 4; ++r) {
            float v0 = acc[m][0][r] + bs0;
            float v1 = acc[m][1][r] + bs1;
            const int rl  = m * 16 + lk * 4 + r;     // local row (C/D layout)
            const int row = r0 + rl;
            if (row < NSEG)
                ((unsigned*)tab)[row * 64 + c0] = cvt_pk_bf16(v0, v1);
            float ps = v0 * ws0 + v1 * ws1;
            float pd = v0 * wd0 + v1 * wd1;
            #pragma unroll
            for (int off = 8; off >= 1; off >>= 1) {  // reduce 16 cols per group
                ps += __shfl_xor(ps, off);
                pd += __shfl_xor(pd, off);
            }
            if (l15 == 0) { ps_part[w][rl] = ps; pd_part[w][rl] = pd; }
        }
    }
    __syncthreads();
    if (tid < 64) {
        const int row = r0 + tid;
        if (row < NSEG) {
            a_src[row] = ps_part[0][tid] + ps_part[1][tid] + ps_part[2][tid] + ps_part[3][tid];
            a_dst[row] = pd_part[0][tid] + pd_part[1][tid] + pd_part[2][tid] + pd_part[3][tid];
        }
    }
}

__device__ __forceinline__ float bf_lo(unsigned u) { return __uint_as_float(u << 16); }
__device__ __forceinline__ float bf_hi(unsigned u) { return __uint_as_float(u & 0xffff0000u); }
__device__ __forceinline__ float bcastf(float v, int j) {
    return __uint_as_float(__builtin_amdgcn_readlane(__float_as_uint(v), j));
}

// agg: one wave per segment; lane l owns features {l, l+64} (one bf16x2 dword,
// matching the tab packing). Proven structure — byte-identical to rounds 4/5.
__global__ __launch_bounds__(256) void agg_kernel(
    const int* __restrict__ dst, const float* __restrict__ a_src,
    const float* __restrict__ a_dst, const float* __restrict__ b_att,
    const int* __restrict__ seg_start, const unsigned int* __restrict__ tab32,
    float* __restrict__ out)
{
    const int wid = blockIdx.x * 4 + (threadIdx.x >> 6);
    if (wid >= NSEG) return;                 // wave-uniform exit
    const int lane = threadIdx.x & 63;
    const unsigned int* tabl = tab32 + lane; // row stride 64 dwords

    const int s0 = seg_start[wid];
    const int s1 = seg_start[wid + 1];
    const float aS = a_src[wid] + b_att[0];

    float accx = 0.f, accy = 0.f, ssum = 0.f;

    for (int cb = s0; cb < s1; cb += 64) {
        int n = s1 - cb; if (n > 64) n = 64;
        int e = cb + lane;
        int dmine = 0; float sc = 0.f;
        if (lane < n) {
            dmine = dst[e] << 6;             // pre-scaled dword row offset
            float att = aS + a_dst[dmine >> 6];
            att = att > 0.f ? att : 0.2f * att;   // leaky_relu 0.2
            sc  = expf(att - 1.f);
        }
        ssum += sc;

        int j = 0;
        for (; j + 7 < n; j += 8) {
            float w0 = bcastf(sc, j+0), w1 = bcastf(sc, j+1);
            float w2 = bcastf(sc, j+2), w3 = bcastf(sc, j+3);
            float w4 = bcastf(sc, j+4), w5 = bcastf(sc, j+5);
            float w6 = bcastf(sc, j+6), w7 = bcastf(sc, j+7);
            int d0 = __builtin_amdgcn_readlane(dmine, j+0);
            int d1 = __builtin_amdgcn_readlane(dmine, j+1);
            int d2 = __builtin_amdgcn_readlane(dmine, j+2);
            int d3 = __builtin_amdgcn_readlane(dmine, j+3);
            int d4 = __builtin_amdgcn_readlane(dmine, j+4);
            int d5 = __builtin_amdgcn_readlane(dmine, j+5);
            int d6 = __builtin_amdgcn_readlane(dmine, j+6);
            int d7 = __builtin_amdgcn_readlane(dmine, j+7);
            unsigned u0 = tabl[d0], u1 = tabl[d1], u2 = tabl[d2], u3 = tabl[d3];
            unsigned u4 = tabl[d4], u5 = tabl[d5], u6 = tabl[d6], u7 = tabl[d7];
            accx += w0 * bf_lo(u0); accy += w0 * bf_hi(u0);
            accx += w1 * bf_lo(u1); accy += w1 * bf_hi(u1);
            accx += w2 * bf_lo(u2); accy += w2 * bf_hi(u2);
            accx += w3 * bf_lo(u3); accy += w3 * bf_hi(u3);
            accx += w4 * bf_lo(u4); accy += w4 * bf_hi(u4);
            accx += w5 * bf_lo(u5); accy += w5 * bf_hi(u5);
            accx += w6 * bf_lo(u6); accy += w6 * bf_hi(u6);
            accx += w7 * bf_lo(u7); accy += w7 * bf_hi(u7);
        }
        for (; j < n; ++j) {
            float w = bcastf(sc, j);
            int   d = __builtin_amdgcn_readlane(dmine, j);
            unsigned u = tabl[d];
            accx += w * bf_lo(u);
            accy += w * bf_hi(u);
        }
    }

    #pragma unroll
    for (int off = 32; off >= 1; off >>= 1) ssum += __shfl_xor(ssum, off);

    const float inv = (s1 > s0) ? 1.f / ssum : 0.f;
    float ox = accx * inv, oy = accy * inv;
    ox = 1.f / (1.f + expf(-ox));
    oy = 1.f / (1.f + expf(-oy));
    out[wid * EMB + lane]      = ox;   // feat lane
    out[wid * EMB + 64 + lane] = oy;   // feat lane+64
}

extern "C" void kernel_launch(void* const* d_in, const int* in_sizes, int n_in,
                              void* d_out, int out_size, void* d_ws, size_t ws_size,
                              hipStream_t stream) {
    const float* emb  = (const float*)d_in[0];   // (20001, 128)
    const int*   edge = (const int*)  d_in[1];   // (640000, 2)
    const float* W    = (const float*)d_in[2];   // (128, 128)
    const float* bsc  = (const float*)d_in[3];   // (128,)
    const float* Watt = (const float*)d_in[4];   // (256,)
    const float* batt = (const float*)d_in[5];   // (1,)
    float* out = (float*)d_out;                  // (20001, 128)

    unsigned short* tab = (unsigned short*)d_ws;            // NSEG*EMB bf16 (5.12 MB)
    float* a_src = (float*)(tab + (size_t)NSEG * EMB);      // NSEG
    float* a_dst = a_src + NSEG;                            // NSEG
    int*   seg_start = (int*)(a_dst + NSEG);                // NSEG+1
    int*   dstc = seg_start + NSEG + 3;                     // NE (compacted dst col)

    prep_kernel<<<SCALE_BLOCKS + BOUNDS_BLOCKS, 256, 0, stream>>>(
        emb, W, bsc, Watt, edge, tab, a_src, a_dst, seg_start, dstc);
    agg_kernel<<<(NSEG + 3) / 4, 256, 0, stream>>>(
        dstc, a_src, a_dst, batt, seg_start, (const unsigned int*)tab, out);
}